// Round 2
// baseline (306.162 us; speedup 1.0000x reference)
//
#include <hip/hip_runtime.h>

// LoRA forward: out = x @ (A @ B * scale)  ==  ((x @ A) * scale) @ B
// x: [4, 2048, 4096] fp32 -> 8192 rows of 4096
// A: [4096, 8] fp32 (row-major)  -> A[i][:] is 8 contiguous floats = 2 float4s
// B: [8, 4096] fp32 (row-major)
// out: [8192, 4096] fp32
//
// R2 theory: R1 kernel was latency-bound (Occ 18.6%, VALUBusy 14%, HBM 29%).
// Causes: (a) block-wide __syncthreads + LDS reduction coupled 4 waves and
// created HBM-silent bubbles; (b) separate transpose dispatch; (c) 2048-block
// grid = 2 occupancy rounds at the 4-blocks/CU VGPR cap.
// Fix: wave-autonomous — each wave owns ROWS=2 rows end-to-end, __shfl_xor
// butterfly reduce (no LDS, no barriers), A loaded directly (A row = 32 B
// contiguous, already coalesced -> transpose kernel deleted), grid = 1024
// blocks = exactly 4 blocks/CU resident in one round. Non-temporal out stores
// keep streaming writes from evicting cached A/B/x.
// R3: compile fix — __builtin_nontemporal_store needs a NATIVE vector type
// (ext_vector_type), not HIP's float4 class. Store through f32x4*.

#define DIM    4096
#define DIM4   (DIM / 4)      // 1024 float4 per row
#define RANK   8
#define LORA_SCALE 2.0f
#define BLOCK  256
#define WPB    4              // waves per block
#define ROWS   2              // x-rows per wave
#define RPB    (WPB * ROWS)   // 8 rows per block
#define ITERS  (DIM4 / 64)    // 16 float4 positions per lane

typedef float f32x4 __attribute__((ext_vector_type(4)));

__device__ __forceinline__ void fma8(float acc[RANK], float xe,
                                     const float4& lo, const float4& hi)
{
    acc[0] += xe * lo.x; acc[1] += xe * lo.y;
    acc[2] += xe * lo.z; acc[3] += xe * lo.w;
    acc[4] += xe * hi.x; acc[5] += xe * hi.y;
    acc[6] += xe * hi.z; acc[7] += xe * hi.w;
}

__global__ __launch_bounds__(BLOCK, 4) void lora_fused_kernel(
    const float* __restrict__ x,
    const float* __restrict__ A,
    const float* __restrict__ B,
    float* __restrict__ out)
{
    const int tid  = threadIdx.x;
    const int wave = tid >> 6;
    const int lane = tid & 63;
    const size_t row0 = (size_t)blockIdx.x * RPB + (size_t)wave * ROWS;

    const float4* __restrict__ x4  = (const float4*)x;
    const float4* __restrict__ A4  = (const float4*)A;   // A4[2*i+j]: A[i][4j..4j+3]
    const float4* __restrict__ B4  = (const float4*)B;
    f32x4* __restrict__ out4 = (f32x4*)out;

    // ---- Phase 1: acc[m][r] = sum_i x[row0+m][i] * A[i][r] (per-lane partials) ----
    float acc[ROWS][RANK];
#pragma unroll
    for (int m = 0; m < ROWS; ++m)
#pragma unroll
        for (int r = 0; r < RANK; ++r) acc[m][r] = 0.0f;

#pragma unroll 2
    for (int k = 0; k < ITERS; ++k) {
        const int i4 = lane + 64 * k;          // float4 index within row
        float4 xa[ROWS];
#pragma unroll
        for (int m = 0; m < ROWS; ++m)
            xa[m] = x4[(row0 + m) * DIM4 + i4];
        // A rows 4*i4 .. 4*i4+3 -> 8 contiguous float4s (128 B per lane)
        float4 a[8];
#pragma unroll
        for (int j = 0; j < 8; ++j)
            a[j] = A4[8 * i4 + j];
#pragma unroll
        for (int m = 0; m < ROWS; ++m) {
            fma8(acc[m], xa[m].x, a[0], a[1]);
            fma8(acc[m], xa[m].y, a[2], a[3]);
            fma8(acc[m], xa[m].z, a[4], a[5]);
            fma8(acc[m], xa[m].w, a[6], a[7]);
        }
    }

    // ---- Phase 2: wave-only butterfly reduce; every lane ends with the sum ----
    float t[ROWS][RANK];
#pragma unroll
    for (int m = 0; m < ROWS; ++m)
#pragma unroll
        for (int r = 0; r < RANK; ++r) {
            float v = acc[m][r];
#pragma unroll
            for (int off = 1; off < 64; off <<= 1)
                v += __shfl_xor(v, off, 64);
            t[m][r] = v * LORA_SCALE;
        }

    // ---- Phase 3: out[row0+m][i] = sum_r t[m][r] * B[r][i] ----
#pragma unroll 2
    for (int k = 0; k < ITERS; ++k) {
        const int i4 = lane + 64 * k;
        float4 b[RANK];
#pragma unroll
        for (int r = 0; r < RANK; ++r)
            b[r] = B4[(size_t)r * DIM4 + i4];
#pragma unroll
        for (int m = 0; m < ROWS; ++m) {
            float4 o;
            o.x = t[m][0] * b[0].x; o.y = t[m][0] * b[0].y;
            o.z = t[m][0] * b[0].z; o.w = t[m][0] * b[0].w;
#pragma unroll
            for (int r = 1; r < RANK; ++r) {
                o.x += t[m][r] * b[r].x;
                o.y += t[m][r] * b[r].y;
                o.z += t[m][r] * b[r].z;
                o.w += t[m][r] * b[r].w;
            }
            f32x4 ov;
            ov.x = o.x; ov.y = o.y; ov.z = o.z; ov.w = o.w;
            __builtin_nontemporal_store(ov, &out4[(row0 + m) * DIM4 + i4]);
        }
    }
}

extern "C" void kernel_launch(void* const* d_in, const int* in_sizes, int n_in,
                              void* d_out, int out_size, void* d_ws, size_t ws_size,
                              hipStream_t stream) {
    const float* x = (const float*)d_in[0];   // [4, 2048, 4096]
    const float* A = (const float*)d_in[1];   // [4096, 8]
    const float* B = (const float*)d_in[2];   // [8, 4096]
    float* out = (float*)d_out;

    const int rows = in_sizes[0] / DIM;       // 8192

    lora_fused_kernel<<<rows / RPB, BLOCK, 0, stream>>>(x, A, B, out);
}

// Round 4
// 267.214 us; speedup vs baseline: 1.1458x; 1.1458x over previous
//
#include <hip/hip_runtime.h>

// LoRA forward: out = x @ (A @ B * scale)  ==  ((x @ A) * scale) @ B
// x: [4, 2048, 4096] fp32 -> 8192 rows of 4096
// A: [4096, 8] fp32 (row-major) -> transposed once to At[8][4096] in ws
// B: [8, 4096] fp32 (row-major)
// out: [8192, 4096] fp32
//
// R3 post-mortem: direct per-lane A loads = 128 B lane stride = address-
// divergent VMEM (64 lines per instruction) -> memory pipe serialized,
// VALUBusy 6.6%, 930 GB/s. The At transpose exists precisely to avoid this.
// R4: wave-autonomous (no LDS, no barriers, butterfly reduce) + transposed
// At (16 B lane stride, coalesced). ROWS=2/wave -> 4096 waves = 16 waves/CU
// = whole problem co-resident in ONE round at launch_bounds(256,4) (VGPR<=128).
// ROWS=2 keeps per-wave At+B traversal amplification at 1 GB L2 traffic
// (~30 us aggregate), under the 43 us HBM floor. NT stores for out.
// R5: resubmit of R4 — previous round was an infra failure (container), the
// kernel never ran.

#define DIM    4096
#define DIM4   (DIM / 4)      // 1024 float4 per row
#define RANK   8
#define LORA_SCALE 2.0f
#define BLOCK  256
#define WPB    4              // waves per block
#define ROWS   2              // x-rows per wave
#define RPB    (WPB * ROWS)   // 8 rows per block
#define ITERS  (DIM4 / 64)    // 16 float4 positions per lane

typedef float f32x4 __attribute__((ext_vector_type(4)));

// ---- Kernel 1: At[r][i] = A[i][r] (tiny; coalesced writes) ----
__global__ __launch_bounds__(BLOCK) void transpose_A_kernel(
    const float* __restrict__ A, float* __restrict__ At)
{
    const int o = blockIdx.x * BLOCK + threadIdx.x;   // 0 .. 8*4096-1
    const int r = o >> 12;                            // 0..7
    const int i = o & (DIM - 1);                      // 0..4095
    At[o] = A[(size_t)i * RANK + r];
}

__device__ __forceinline__ void fma8x4(float acc[RANK], const float4& xv,
                                       const float4 a[RANK])
{
#pragma unroll
    for (int r = 0; r < RANK; ++r) {
        acc[r] += xv.x * a[r].x + xv.y * a[r].y
                + xv.z * a[r].z + xv.w * a[r].w;
    }
}

// ---- Kernel 2: fused ((x@A)*s)@B, wave-autonomous, 2 rows per wave ----
__global__ __launch_bounds__(BLOCK, 4) void lora_fused_kernel(
    const float* __restrict__ x,
    const float* __restrict__ At,
    const float* __restrict__ B,
    float* __restrict__ out)
{
    const int tid  = threadIdx.x;
    const int wave = tid >> 6;
    const int lane = tid & 63;
    const size_t row0 = (size_t)blockIdx.x * RPB + (size_t)wave * ROWS;

    const float4* __restrict__ x4  = (const float4*)x;
    const float4* __restrict__ At4 = (const float4*)At;  // At4[r*DIM4 + i4]
    const float4* __restrict__ B4  = (const float4*)B;
    f32x4* __restrict__ out4 = (f32x4*)out;

    // ---- Phase 1: per-lane partials acc[m][r] = sum_i x[row0+m][i]*At[r][i] ----
    float acc[ROWS][RANK];
#pragma unroll
    for (int m = 0; m < ROWS; ++m)
#pragma unroll
        for (int r = 0; r < RANK; ++r) acc[m][r] = 0.0f;

#pragma unroll 2
    for (int k = 0; k < ITERS; ++k) {
        const int i4 = lane + 64 * k;          // float4 index within row
        float4 a[RANK];
#pragma unroll
        for (int r = 0; r < RANK; ++r)
            a[r] = At4[(size_t)r * DIM4 + i4]; // 16 B lane stride: coalesced
        float4 xa[ROWS];
#pragma unroll
        for (int m = 0; m < ROWS; ++m)
            xa[m] = x4[(row0 + m) * DIM4 + i4];
#pragma unroll
        for (int m = 0; m < ROWS; ++m)
            fma8x4(acc[m], xa[m], a);
    }

    // ---- Phase 2: wave-only butterfly reduce; every lane ends with the sum ----
    float t[ROWS][RANK];
#pragma unroll
    for (int m = 0; m < ROWS; ++m)
#pragma unroll
        for (int r = 0; r < RANK; ++r) {
            float v = acc[m][r];
#pragma unroll
            for (int off = 1; off < 64; off <<= 1)
                v += __shfl_xor(v, off, 64);
            t[m][r] = v * LORA_SCALE;
        }

    // ---- Phase 3: out[row0+m][i] = sum_r t[m][r] * B[r][i] ----
#pragma unroll 2
    for (int k = 0; k < ITERS; ++k) {
        const int i4 = lane + 64 * k;
        float4 b[RANK];
#pragma unroll
        for (int r = 0; r < RANK; ++r)
            b[r] = B4[(size_t)r * DIM4 + i4];  // coalesced
#pragma unroll
        for (int m = 0; m < ROWS; ++m) {
            float4 o;
            o.x = t[m][0] * b[0].x; o.y = t[m][0] * b[0].y;
            o.z = t[m][0] * b[0].z; o.w = t[m][0] * b[0].w;
#pragma unroll
            for (int r = 1; r < RANK; ++r) {
                o.x += t[m][r] * b[r].x;
                o.y += t[m][r] * b[r].y;
                o.z += t[m][r] * b[r].z;
                o.w += t[m][r] * b[r].w;
            }
            f32x4 ov;
            ov.x = o.x; ov.y = o.y; ov.z = o.z; ov.w = o.w;
            __builtin_nontemporal_store(ov, &out4[(row0 + m) * DIM4 + i4]);
        }
    }
}

extern "C" void kernel_launch(void* const* d_in, const int* in_sizes, int n_in,
                              void* d_out, int out_size, void* d_ws, size_t ws_size,
                              hipStream_t stream) {
    const float* x = (const float*)d_in[0];   // [4, 2048, 4096]
    const float* A = (const float*)d_in[1];   // [4096, 8]
    const float* B = (const float*)d_in[2];   // [8, 4096]
    float* out = (float*)d_out;
    float* At  = (float*)d_ws;                // 8*4096 floats = 128 KiB

    const int rows = in_sizes[0] / DIM;       // 8192

    transpose_A_kernel<<<(RANK * DIM) / BLOCK, BLOCK, 0, stream>>>(A, At);
    lora_fused_kernel<<<rows / RPB, BLOCK, 0, stream>>>(x, At, B, out);
}